// Round 10
// baseline (47.416 us; speedup 1.0000x reference)
//
#include <hip/hip_runtime.h>
#include <hip/hip_bf16.h>
#include <math.h>

using short8   = __attribute__((ext_vector_type(8))) short;
using ushort4v = __attribute__((ext_vector_type(4))) unsigned short;
using float4v  = __attribute__((ext_vector_type(4))) float;

#define D_DIM 1024
#define NCLS  40
#define WSTR  1064
#define TM    64            // rows per block (4 waves x 16)
#define CW    256           // K-chunk width (cols) -> 4 chunks

__device__ __forceinline__ short f2bf(float f) {
    __hip_bfloat16 h = __float2bfloat16(f);
    union { __hip_bfloat16 h; short s; } u; u.h = h;
    return u.s;
}

// ---- Kernel 1: pack W/W_rev into MFMA-fragment order (verified):
//      Wfrag[(kk*5+t)*512 + lane*8 + e] = class(t*16+lane&15), k = kk*32+(lane>>4)*8+e
__global__ void convert_w_kernel(const float* __restrict__ W, const float* __restrict__ Wr,
                                 short* __restrict__ Wfrag) {
    int idx  = blockIdx.x * 256 + threadIdx.x;   // 0..10239
    int lane = idx & 63;
    int rest = idx >> 6;          // kk*5 + t, kk = 0..31
    int t    = rest % 5;
    int kk   = rest / 5;
    int cls  = t * 16 + (lane & 15);
    int k0   = kk * 32 + (lane >> 4) * 8;
    const float* srow = (cls < NCLS) ? (W + (size_t)cls * WSTR)
                                     : (Wr + (size_t)(cls - NCLS) * WSTR);
    short8 v;
#pragma unroll
    for (int e = 0; e < 8; ++e) v[e] = f2bf(srow[k0 + e]);
    *(short8*)(Wfrag + (size_t)idx * 8) = v;
}

// ---- Kernel 2: contiguous-per-instruction A staging (m13 pattern) + MFMA + chain
__global__ __launch_bounds__(256, 2) void bichain_main(
    const float* __restrict__ src, const short* __restrict__ Wfrag,
    const float* __restrict__ Wf, const float* __restrict__ Wr,
    const float* __restrict__ bf_, const float* __restrict__ br_,
    float* __restrict__ out)
{
    // LDS: 4 waves x 2 bufs x [16 rows][512B bf16] = 64KB; epilogue reuses as Lg[64][81]
    __shared__ __align__(16) char smem[65536];

    const int tid  = threadIdx.x;
    const int lane = tid & 63;
    const int wave = tid >> 6;
    const int row0 = blockIdx.x * TM;
    const int i16  = lane & 15;      // fragment: A row
    const int i4   = lane >> 4;      // fragment: k octet
    const int sw7  = i16 & 7;

    char* ldsW = smem + wave * 16384;            // this wave's 2 buffers
    // A load base: instr r covers row (row0+wave*16+r), cols lane*4..+3 of the chunk
    // -> 64 lanes x 16B = 1KB CONTIGUOUS per instruction (the 6.3 TB/s pattern)
    const float* aBase = src + (size_t)(row0 + wave * 16) * D_DIM + lane * 4;

    float4v ap[16];      // one full chunk (16 rows) in flight
    short8  wp[2][5];    // W fragments, parity = ks&1 (compile-time)
    float4v acc[5];
#pragma unroll
    for (int t = 0; t < 5; ++t)
#pragma unroll
        for (int r = 0; r < 4; ++r) acc[t][r] = 0.f;

    auto loadA = [&](int ch) {                   // 16 x 1KB contiguous loads
        const float* p = aBase + ch * CW;
#pragma unroll
        for (int r = 0; r < 16; ++r)
            ap[r] = *(const float4v*)(p + (size_t)r * D_DIM);
    };
    auto dsw = [&](int bufi) {                   // cvt + swizzled ds_write_b64
        char* b = ldsW + bufi * 8192;
        const int so = (lane >> 1);              // 16B slot, (lane&1) = 8B half
#pragma unroll
        for (int r = 0; r < 16; ++r) {
            ushort4v v;
            v[0] = (unsigned short)f2bf(ap[r][0]);
            v[1] = (unsigned short)f2bf(ap[r][1]);
            v[2] = (unsigned short)f2bf(ap[r][2]);
            v[3] = (unsigned short)f2bf(ap[r][3]);
            *(ushort4v*)(b + r * 512 + ((so ^ (r & 7)) << 4) + (lane & 1) * 8) = v;
        }
    };

#define LOADW(kk, sl) do { if ((kk) < 32) {                                \
    const short* _w = Wfrag + (size_t)(kk) * 2560 + (lane << 3);           \
    wp[sl][0] = *(const short8*)(_w + 0 * 512);                            \
    wp[sl][1] = *(const short8*)(_w + 1 * 512);                            \
    wp[sl][2] = *(const short8*)(_w + 2 * 512);                            \
    wp[sl][3] = *(const short8*)(_w + 3 * 512);                            \
    wp[sl][4] = *(const short8*)(_w + 4 * 512); } } while (0)

// fragment read (swizzled slot s = ks*4+i4) + 5 MFMA; buf = ch&1, wp slot = ks&1
#define MFMAK(ch, ks) do {                                                 \
    const char* _fb = ldsW + ((ch) & 1) * 8192 + i16 * 512;                \
    short8 _a = *(const short8*)(_fb + ((((ks) * 4 + i4) ^ sw7) << 4));    \
    acc[0] = __builtin_amdgcn_mfma_f32_16x16x32_bf16(_a, wp[(ks)&1][0], acc[0], 0, 0, 0); \
    acc[1] = __builtin_amdgcn_mfma_f32_16x16x32_bf16(_a, wp[(ks)&1][1], acc[1], 0, 0, 0); \
    acc[2] = __builtin_amdgcn_mfma_f32_16x16x32_bf16(_a, wp[(ks)&1][2], acc[2], 0, 0, 0); \
    acc[3] = __builtin_amdgcn_mfma_f32_16x16x32_bf16(_a, wp[(ks)&1][3], acc[3], 0, 0, 0); \
    acc[4] = __builtin_amdgcn_mfma_f32_16x16x32_bf16(_a, wp[(ks)&1][4], acc[4], 0, 0, 0); \
  } while (0)

// step: prefetch next W slice, then consume current (W is L2-hot; A overlap via chunk depth)
#define CSTEP(ch, ks) do { LOADW((ch) * 8 + (ks) + 1, ((ks) + 1) & 1); MFMAK(ch, ks); } while (0)
#define COMPUTE(ch) do { CSTEP(ch,0); CSTEP(ch,1); CSTEP(ch,2); CSTEP(ch,3);               \
                         CSTEP(ch,4); CSTEP(ch,5); CSTEP(ch,6); CSTEP(ch,7); } while (0)
#define SB __builtin_amdgcn_sched_barrier(0)

    // prologue: chunk 0 staged, first W slice in flight
    loadA(0); dsw(0); LOADW(0, 0);
    // pipeline: issue chunk ch+1's 16 contiguous loads, pin them, compute ch, then stage ch+1
    loadA(1); SB; COMPUTE(0); dsw(1);
    loadA(2); SB; COMPUTE(1); dsw(0);
    loadA(3); SB; COMPUTE(2); dsw(1);
               SB; COMPUTE(3);

#undef LOADW
#undef MFMAK
#undef CSTEP
#undef COMPUTE
#undef SB

    __syncthreads();   // all waves done with private LDS before reuse

    // ---- logits -> LDS  (C/D layout: col = lane&15, row = (lane>>4)*4 + reg)
    float* Lg = (float*)smem;   // [64][81]
#pragma unroll
    for (int t = 0; t < 5; ++t)
#pragma unroll
        for (int r = 0; r < 4; ++r) {
            int row = wave * 16 + i4 * 4 + r;
            int cls = t * 16 + i16;
            Lg[row * 81 + cls] = acc[t][r];
        }
    __syncthreads();

    // ---- sequential chain, fp32, one thread per (row, direction); scores in-place
    if (tid < 128) {
        const int row = tid >> 1;
        const int dir = tid & 1;
        const float* Wt = dir ? Wr : Wf;
        const float* bi = dir ? br_ : bf_;
        float s[NCLS];
#pragma unroll
        for (int i = 0; i < NCLS; ++i) {
            float z = Lg[row * 81 + dir * NCLS + i] + bi[i];
#pragma unroll
            for (int j = 0; j < i; ++j)
                z += s[j] * Wt[i * WSTR + D_DIM + j];
            s[i] = 1.f / (1.f + __expf(-z));
            Lg[row * 81 + dir * NCLS + i] = s[i];
        }
    }
    __syncthreads();

    // ---- combine + coalesced write: out[:,c] = 0.5*(fwd[c] + rev[39-c])
    float* outp = out + (size_t)row0 * NCLS;
    for (int idx = tid; idx < TM * NCLS; idx += 256) {
        int row = idx / NCLS;
        int c   = idx - row * NCLS;
        outp[idx] = 0.5f * (Lg[row * 81 + c] + Lg[row * 81 + NCLS + (NCLS - 1 - c)]);
    }
}

extern "C" void kernel_launch(void* const* d_in, const int* in_sizes, int n_in,
                              void* d_out, int out_size, void* d_ws, size_t ws_size,
                              hipStream_t stream) {
    const float* src = (const float*)d_in[0];
    // d_in[1] = attn_mask, unused by the reference
    const float* W   = (const float*)d_in[2];
    const float* b   = (const float*)d_in[3];
    const float* Wr  = (const float*)d_in[4];
    const float* br  = (const float*)d_in[5];
    float* out = (float*)d_out;
    short* Wfrag = (short*)d_ws;   // 160KB fragment-ordered bf16 weights

    convert_w_kernel<<<40, 256, 0, stream>>>(W, Wr, Wfrag);
    bichain_main<<<512, 256, 0, stream>>>(src, Wfrag, W, Wr, b, br, out);
}